// Round 6
// baseline (1022.562 us; speedup 1.0000x reference)
//
#include <hip/hip_runtime.h>
#include <math.h>

#define DIM 7168
#define NE 256
#define NG 8
#define GSZ 32
#define TOPG 4
#define TOPK_N 8
#define BM 32
#define BK 16
#define NTHR 512
#define NCHUNK (DIM / BK)   // 448

__global__ __launch_bounds__(NTHR) void gate_kernel(
    const float* __restrict__ x, const float* __restrict__ w,
    const float* __restrict__ bias, float* __restrict__ out, int n)
{
    // 64 KB LDS union:
    //   staging: w2[2][16][256] f32 (32 KB) + x2[2][16][34] f64 (8.7 KB)
    //   overlay: sc[256][32] f64 (64 KB), used only after GEMM completes
    __shared__ __align__(16) char smem[65536];
    float  (*w2)[BK][NE] = reinterpret_cast<float(*)[BK][NE]>(smem);          // [2][16][256]
    double (*x2)[BK][34] = reinterpret_cast<double(*)[BK][34]>(smem + 32768); // [2][16][34]
    double (*sc)[BM]     = reinterpret_cast<double(*)[BM]>(smem);             // overlay [256][32]

    const int t    = threadIdx.x;
    const int row0 = blockIdx.x * BM;

    // ---- staging assignment ----
    const int  we = t & 255;            // expert staged by this thread
    const int  h8 = (t >> 8) * 8;       // k-half 0 or 8
    const long wbase = (long)we * DIM + h8;
    const int  rx = t >> 2;             // x row (t<128)
    const int  kx = (t & 3) * 4;        // x k quad
    int rr = row0 + rx; if (rr > n - 1) rr = n - 1;
    const long xbase = (long)rr * DIM + kx;

    // ---- compute assignment: wave = (row-group, expert-half) ----
    const int wv   = t >> 6;            // 0..7
    const int lane = t & 63;
    const int h    = wv & 1;            // expert half
    const int rg   = wv >> 1;           // row group 0..3
    const int rb   = 8 * rg;            // rows rb..rb+7
    const int e0   = 128 * h + 2 * lane; // experts e0, e0+1

    double acc[8][2];
#pragma unroll
    for (int i = 0; i < 8; ++i) { acc[i][0] = 0.0; acc[i][1] = 0.0; }

    // prefetch chunk 0
    float4 wra = *(const float4*)&w[wbase];
    float4 wrb = *(const float4*)&w[wbase + 4];
    float4 xr  = make_float4(0.f, 0.f, 0.f, 0.f);
    if (t < 128) xr = *(const float4*)&x[xbase];

    for (int c = 0; c < NCHUNK; ++c) {
        const int b = c & 1;
        // ---- write staged chunk c into buffer b (w stays f32; x cvt'd here) ----
        {
            const float* fa = reinterpret_cast<const float*>(&wra);
            const float* fb = reinterpret_cast<const float*>(&wrb);
#pragma unroll
            for (int q = 0; q < 4; ++q) {
                w2[b][h8 + q][we]     = fa[q];
                w2[b][h8 + 4 + q][we] = fb[q];
            }
            if (t < 128) {
                const float* fx = reinterpret_cast<const float*>(&xr);
#pragma unroll
                for (int q = 0; q < 4; ++q) x2[b][kx + q][rx] = (double)fx[q];
            }
        }
        // ---- issue chunk c+1 global loads (in flight under compute) ----
        {
            const long k0 = (long)((c + 1 < NCHUNK) ? c + 1 : c) * BK;
            wra = *(const float4*)&w[wbase + k0];
            wrb = *(const float4*)&w[wbase + k0 + 4];
            if (t < 128) xr = *(const float4*)&x[xbase + k0];
        }
        __syncthreads();   // buffer b fully staged; buf b^1's readers (c-1) all done
        // ---- compute chunk c from buffer b ----
#pragma unroll
        for (int kk = 0; kk < BK; ++kk) {
            const float2 wf = *reinterpret_cast<const float2*>(&w2[b][kk][e0]);
            const double wd0 = (double)wf.x;
            const double wd1 = (double)wf.y;
            const double2 xp0 = *reinterpret_cast<const double2*>(&x2[b][kk][rb]);
            const double2 xp1 = *reinterpret_cast<const double2*>(&x2[b][kk][rb + 2]);
            const double2 xp2 = *reinterpret_cast<const double2*>(&x2[b][kk][rb + 4]);
            const double2 xp3 = *reinterpret_cast<const double2*>(&x2[b][kk][rb + 6]);
            const double xv[8] = {xp0.x, xp0.y, xp1.x, xp1.y,
                                  xp2.x, xp2.y, xp3.x, xp3.y};
#pragma unroll
            for (int i = 0; i < 8; ++i) {
                acc[i][0] = fma(xv[i], wd0, acc[i][0]);
                acc[i][1] = fma(xv[i], wd1, acc[i][1]);
            }
        }
    }

    __syncthreads();   // all compute done; safe to overlay sc
#pragma unroll
    for (int j = 0; j < 2; ++j)
#pragma unroll
        for (int q = 0; q < 4; ++q) {
            double2 v; v.x = acc[2 * q][j]; v.y = acc[2 * q + 1][j];
            *reinterpret_cast<double2*>(&sc[e0 + j][rb + 2 * q]) = v;
        }
    __syncthreads();

    // ---- routing: verbatim (serial per row, sc transposed [e][row]) ----
    if (t < BM) {
        const int row = row0 + t;
        if (row < n) {
            double zmax = -1e300;
            for (int e = 0; e < NE; ++e) zmax = fmax(zmax, sc[e][t]);
            double Z = 0.0;
            for (int e = 0; e < NE; ++e) {
                double p = exp(sc[e][t] - zmax);
                sc[e][t] = p;           // column t private to this thread
                Z += p;
            }
            const double invZ = 1.0 / Z;

            double gs[NG];
            for (int g = 0; g < NG; ++g) {
                double m1 = -1e300, m2 = -1e300;
                for (int i = 0; i < GSZ; ++i) {
                    double v = sc[g * GSZ + i][t] * invZ + (double)bias[g * GSZ + i];
                    if (v > m1) { m2 = m1; m1 = v; }
                    else if (v > m2) { m2 = v; }
                }
                gs[g] = m1 + m2;
            }
            unsigned keep = 0;
            for (int tt = 0; tt < TOPG; ++tt) {
                double best = -1e300; int bg = 0;
                for (int g = 0; g < NG; ++g)
                    if (!((keep >> g) & 1u) && gs[g] > best) { best = gs[g]; bg = g; }
                keep |= 1u << bg;
            }
            unsigned long long tk[4] = {0ull, 0ull, 0ull, 0ull};
            float* out_w = out;
            float* out_i = out + (size_t)n * TOPK_N;
            for (int pp = 0; pp < TOPK_N; ++pp) {
                double best = -1e300; int be = 0;
                for (int e = 0; e < NE; ++e) {
                    if (!((keep >> (e >> 5)) & 1u)) continue;
                    if ((tk[e >> 6] >> (e & 63)) & 1ull) continue;
                    double s = sc[e][t] * invZ + (double)bias[e];
                    if (s > best) { best = s; be = e; }
                }
                tk[be >> 6] |= 1ull << (be & 63);
                out_w[(size_t)row * TOPK_N + pp] = (float)(sc[be][t] * invZ * 2.5);
                out_i[(size_t)row * TOPK_N + pp] = (float)be;
            }
        }
    }
}

extern "C" void kernel_launch(void* const* d_in, const int* in_sizes, int n_in,
                              void* d_out, int out_size, void* d_ws, size_t ws_size,
                              hipStream_t stream) {
    const float* x  = (const float*)d_in[0];
    const float* w  = (const float*)d_in[1];
    const float* b  = (const float*)d_in[2];
    float* out      = (float*)d_out;
    const int n     = in_sizes[0] / DIM;
    const int nblk  = (n + BM - 1) / BM;
    gate_kernel<<<nblk, NTHR, 0, stream>>>(x, w, b, out, n);
}